// Round 5
// baseline (532.635 us; speedup 1.0000x reference)
//
#include <hip/hip_runtime.h>

// NAM inference via rank-sliced sorted-prefix decomposition (full fp32, no MFMA).
// h_u = clip(d*e_u,0,1), d = x[b,f]-exu_b[f], e_u = exp(exu_w[f,u]) > 0.
//   d <= 0        -> h = 0     -> h2 = relu(b1)            (per-f table)
//   d*emin >= 1   -> h = 1 all -> h2 = relu(colsum + b1)   (per-f table, exact)
//   middle        -> h_u = min(d*e_u,1). With u sorted by e_u ascending and
//                    r = #{e_u < 1/d}:  hT W1 = d*S_r - T_r + colsum, where
//                    S_r,T_r are prefix sums of (e_u*W1row, W1row) in sorted order.
// The sorted stream is split into 8 rank-slices per f (linearity of prefix sums):
// each (f,slice) block emits slice-LOCAL snapshots + slice totals; finalize adds
// the exclusive slice prefix. W1 (268 MB) is read exactly once.
// B=2048, F=128, U=1024, V=512, C=10.

#define F_ 128
#define U_ 1024
#define V_ 512
#define C_ 10
#define B_ 2048
#define NSL 8
#define SLW 128          // rows per slice
#define UN 16            // prefetch depth (rows)

typedef __attribute__((ext_vector_type(2))) float f2;
typedef __attribute__((ext_vector_type(4))) float fx4;

__device__ __forceinline__ float ebits(unsigned long long k) {
  return __builtin_bit_cast(float, (unsigned)(k >> 32));
}

// ---------------- K1: per-f bitonic sort of (e_bits,u); emin; biasc; zero logits ----------------
__global__ void nam_sort(const float* __restrict__ exu_w, const float* __restrict__ b2,
                         const float* __restrict__ b_out,
                         unsigned long long* __restrict__ skeys_g,
                         float* __restrict__ emin, float* __restrict__ biasc,
                         int* __restrict__ count, float* __restrict__ logits_mid)
{
  const int bid = blockIdx.x, t = threadIdx.x;
  if (bid < F_) {
    __shared__ unsigned long long keys[1024];
    for (int i = t; i < U_; i += 256) {
      float e = expf(exu_w[(size_t)bid * U_ + i]);
      keys[i] = ((unsigned long long)__builtin_bit_cast(unsigned, e) << 32) | (unsigned)i;
    }
    __syncthreads();
    for (int k = 2; k <= 1024; k <<= 1)
      for (int j = k >> 1; j > 0; j >>= 1) {
        for (int i = t; i < 1024; i += 256) {
          const int p = i ^ j;
          if (p > i) {
            unsigned long long a = keys[i], b = keys[p];
            const bool up = ((i & k) == 0);
            if (up ? (a > b) : (a < b)) { keys[i] = b; keys[p] = a; }
          }
        }
        __syncthreads();
      }
    for (int i = t; i < 1024; i += 256) skeys_g[(size_t)bid * U_ + i] = keys[i];
    if (t == 0) emin[bid] = ebits(keys[0]);
  } else if (bid == F_) {
    if (t < C_) {
      float s = b_out[t];
      for (int ff = 0; ff < F_; ++ff) s += b2[ff * C_ + t];
      biasc[t] = s;
    } else if (t >= 32 && t < 32 + F_) {
      count[t - 32] = 0;
    }
  } else {
    const int idx = (bid - F_ - 1) * 256 + t;   // 80 blocks -> 20480 = B_*C_
    logits_mid[idx] = 0.f;
  }
}

// ---------------- K2: classify rows, build per-feature middle lists ----------------
__global__ void nam_classify(const float* __restrict__ x, const float* __restrict__ exu_b,
                             const float* __restrict__ emin,
                             int* __restrict__ count, int* __restrict__ listb)
{
  const int t = threadIdx.x;
  const int f = t & 127, sub = t >> 7;
  const int b = blockIdx.x * 2 + sub;
  const float d = x[(size_t)b * F_ + f] - exu_b[f];
  if (d > 0.f && d * emin[f] < 1.f) {
    const int idx = atomicAdd(count + f, 1);
    listb[f * B_ + idx] = b;
  }
}

// ---------------- K3: rank-sliced sorted stream over W1 ----------------
// Grid: 1024 = f(128) x slice(8). Block: 256 thr; thread owns 2 v cols (full 2KB rows).
__global__ __launch_bounds__(256) void nam_stream2(
    const float* __restrict__ x, const float* __restrict__ exu_b,
    const float* __restrict__ W1,
    const unsigned long long* __restrict__ skeys_g,
    const int* __restrict__ listb, const int* __restrict__ count,
    float* __restrict__ sliceS, float* __restrict__ sliceT,
    float* __restrict__ h2pre, int* __restrict__ rnk,
    float* __restrict__ ddv, int* __restrict__ bout)
{
  __shared__ unsigned long long skeys[1024];  // full sorted keys (binary search)
  __shared__ unsigned pkey[2048];             // (r_local<<12 | list_idx), sorted
  __shared__ int cnt_s;

  const int f   = blockIdx.x >> 3;
  const int sl  = blockIdx.x & 7;
  const int tid = threadIdx.x;

  for (int i = tid; i < 1024; i += 256) skeys[i] = skeys_g[(size_t)f * U_ + i];
  if (tid == 0) cnt_s = 0;
  const int nmid = count[f];
  const float bfv = exu_b[f];
  __syncthreads();

  // collect this slice's middle rows (rank via binary search on sorted e)
  for (int i = tid; i < nmid; i += 256) {
    const int b = listb[f * B_ + i];
    const float d = x[(size_t)b * F_ + f] - bfv;
    const float thr = 1.0f / d;
    int lo = 0, hi = 1024;
    while (lo < hi) {
      const int mid = (lo + hi) >> 1;
      if (ebits(skeys[mid]) < thr) lo = mid + 1; else hi = mid;
    }
    int s_of = lo >> 7; if (s_of > 7) s_of = 7;   // r=1024 -> slice 7, local 128
    if (s_of == sl) {
      const int pos = atomicAdd(&cnt_s, 1);
      pkey[pos] = ((unsigned)(lo - sl * SLW) << 12) | (unsigned)i;
    }
  }
  __syncthreads();
  const int cnt = cnt_s;
  int npow2 = 1; while (npow2 < cnt) npow2 <<= 1; if (npow2 < 2) npow2 = 2;
  for (int i = tid; i < npow2; i += 256)
    if (i >= cnt) pkey[i] = 0xFFFFFFFFu;
  __syncthreads();
  if (cnt > 1) {
    for (int k = 2; k <= npow2; k <<= 1)
      for (int j = k >> 1; j > 0; j >>= 1) {
        for (int i = tid; i < npow2; i += 256) {
          const int p = i ^ j;
          if (p > i) {
            unsigned a = pkey[i], b = pkey[p];
            const bool up = ((i & k) == 0);
            if (up ? (a > b) : (a < b)) { pkey[i] = b; pkey[p] = a; }
          }
        }
        __syncthreads();
      }
  }

  // ---- stream 128 sorted rows (contiguous 2KB each), prefix-accumulate ----
  const float* Wf = W1 + (size_t)f * (U_ * V_) + 2 * tid;
  const int kb = sl * SLW;
  f2 cur[UN], nxt[UN];
  float ecur[UN], enxt[UN];
#pragma unroll
  for (int q = 0; q < UN; ++q) {
    const unsigned long long kk = skeys[kb + q];
    cur[q] = *(const f2*)(Wf + ((size_t)(unsigned)(kk & 1023u) << 9));
    ecur[q] = ebits(kk);
  }
  float S0 = 0.f, S1 = 0.f, T0 = 0.f, T1 = 0.f;
  int pp = 0;
  int next_rl = (cnt > 0) ? (int)(pkey[0] >> 12) : (1 << 20);

#define EMIT()                                                                   \
  {                                                                              \
    const unsigned pk = pkey[pp];                                                \
    const int li = (int)(pk & 0xFFFu);                                           \
    const int bb = listb[f * B_ + li];                                           \
    const float dd = x[(size_t)bb * F_ + f] - bfv;                               \
    f2 o; o.x = dd * S0 - T0; o.y = dd * S1 - T1;                                \
    *(f2*)(h2pre + (size_t)(f * B_ + li) * V_ + 2 * tid) = o;                    \
    if (tid == 0) {                                                              \
      bout[f * B_ + li] = bb;                                                    \
      ddv[f * B_ + li]  = dd;                                                    \
      rnk[f * B_ + li]  = kb + (int)(pk >> 12);                                  \
    }                                                                            \
    ++pp;                                                                        \
    next_rl = (pp < cnt) ? (int)(pkey[pp] >> 12) : (1 << 20);                    \
  }

  for (int blk = 0; blk < SLW / UN; ++blk) {
    if (blk < SLW / UN - 1) {
#pragma unroll
      for (int q = 0; q < UN; ++q) {
        const unsigned long long kk = skeys[kb + (blk + 1) * UN + q];
        nxt[q] = *(const f2*)(Wf + ((size_t)(unsigned)(kk & 1023u) << 9));
        enxt[q] = ebits(kk);
      }
    }
#pragma unroll
    for (int q = 0; q < UN; ++q) {
      const int j = blk * UN + q;
      while (pp < cnt && next_rl <= j) EMIT();   // snapshot BEFORE row j
      const float e = ecur[q];
      const f2 wv = cur[q];
      S0 = fmaf(e, wv.x, S0);
      S1 = fmaf(e, wv.y, S1);
      T0 += wv.x;
      T1 += wv.y;
    }
#pragma unroll
    for (int q = 0; q < UN; ++q) { cur[q] = nxt[q]; ecur[q] = enxt[q]; }
  }
  while (pp < cnt) EMIT();   // r_local == 128 (slice 7: all-active rows)
#undef EMIT

  // slice totals
  {
    f2 sv; sv.x = S0; sv.y = S1;
    f2 tv; tv.x = T0; tv.y = T1;
    *(f2*)(sliceS + (size_t)(f * NSL + sl) * V_ + 2 * tid) = sv;
    *(f2*)(sliceT + (size_t)(f * NSL + sl) * V_ + 2 * tid) = tv;
  }
}

// ---------------- K4: finalize middles + zero/one tables (fused) ----------------
// Grid: 128 (per f). Block: 256 thr = 4 waves.
__global__ __launch_bounds__(256) void nam_finmid(
    const int* __restrict__ count, const int* __restrict__ rnk,
    const float* __restrict__ ddv, const int* __restrict__ bout,
    const float* __restrict__ h2pre,
    const float* __restrict__ sliceS, const float* __restrict__ sliceT,
    const float* __restrict__ b1, const float* __restrict__ W2,
    float* __restrict__ zlog, float* __restrict__ olog,
    float* __restrict__ logits_mid)
{
  __shared__ float Sx[NSL * V_];   // exclusive prefix of slice S totals
  __shared__ float Tx[NSL * V_];   // exclusive prefix of slice T totals
  __shared__ float CB[V_];         // colsum + b1
  __shared__ float red[4][2 * C_];

  const int f = blockIdx.x, tid = threadIdx.x;
  const int wave = tid >> 6, lane = tid & 63;

  // build exclusive prefixes + colsum; fused zero/one tables
  float a0[C_], a1[C_];
#pragma unroll
  for (int c = 0; c < C_; ++c) { a0[c] = 0.f; a1[c] = 0.f; }
#pragma unroll
  for (int k = 0; k < 2; ++k) {
    const int v = 2 * tid + k;
    float accS = 0.f, accT = 0.f;
#pragma unroll
    for (int s = 0; s < NSL; ++s) {
      Sx[s * V_ + v] = accS;
      Tx[s * V_ + v] = accT;
      accS += sliceS[(size_t)(f * NSL + s) * V_ + v];
      accT += sliceT[(size_t)(f * NSL + s) * V_ + v];
    }
    const float b1v = b1[(size_t)f * V_ + v];
    CB[v] = accT + b1v;                      // colsum + b1
    const float hz = fmaxf(b1v, 0.f);
    const float ho = fmaxf(accT + b1v, 0.f);
    const float* w2p = W2 + ((size_t)f * V_ + v) * C_;
#pragma unroll
    for (int c = 0; c < C_; ++c) {
      const float wv = w2p[c];
      a0[c] = fmaf(hz, wv, a0[c]);
      a1[c] = fmaf(ho, wv, a1[c]);
    }
  }
#pragma unroll
  for (int off = 32; off > 0; off >>= 1)
#pragma unroll
    for (int c = 0; c < C_; ++c) {
      a0[c] += __shfl_down(a0[c], off);
      a1[c] += __shfl_down(a1[c], off);
    }
  if (lane == 0)
#pragma unroll
    for (int c = 0; c < C_; ++c) { red[wave][c] = a0[c]; red[wave][C_ + c] = a1[c]; }
  __syncthreads();
  if (tid < 2 * C_) {
    const float s = red[0][tid] + red[1][tid] + red[2][tid] + red[3][tid];
    if (tid < C_) zlog[tid * F_ + f] = s;
    else          olog[(tid - C_) * F_ + f] = s;
  }

  // middle rows: h2 = relu(pre + d*Sx[s] - Tx[s] + colsum + b1); logits += h2 @ W2
  const int nmid = count[f];
  for (int row = wave; row < nmid; row += 4) {
    const float d = ddv[f * B_ + row];
    const int   r = rnk[f * B_ + row];
    const int   b = bout[f * B_ + row];
    int s = r >> 7; if (s > 7) s = 7;
    const float* pre = h2pre + (size_t)(f * B_ + row) * V_;
    float acc[C_];
#pragma unroll
    for (int c = 0; c < C_; ++c) acc[c] = 0.f;
#pragma unroll
    for (int j = 0; j < 8; ++j) {
      const int v = lane + 64 * j;     // stride-64: conflict-free LDS, coalesced global
      const float h = fmaxf(pre[v] + d * Sx[s * V_ + v] - Tx[s * V_ + v] + CB[v], 0.f);
      const float* w2p = W2 + ((size_t)f * V_ + v) * C_;
#pragma unroll
      for (int c = 0; c < C_; ++c) acc[c] = fmaf(h, w2p[c], acc[c]);
    }
#pragma unroll
    for (int off = 32; off > 0; off >>= 1)
#pragma unroll
      for (int c = 0; c < C_; ++c) acc[c] += __shfl_down(acc[c], off);
    if (lane == 0)
#pragma unroll
      for (int c = 0; c < C_; ++c) atomicAdd(logits_mid + (size_t)b * C_ + c, acc[c]);
  }
}

// ---------------- K5: gather per-row contributions + softmax ----------------
__global__ void nam_final(const float* __restrict__ x, const float* __restrict__ exu_b,
                          const float* __restrict__ emin,
                          const float* __restrict__ zlog, const float* __restrict__ olog,
                          const float* __restrict__ biasc, const float* __restrict__ logits_mid,
                          float* __restrict__ out)
{
  const int t = threadIdx.x;
  const int f = t & 127, sub = t >> 7;
  const int b = blockIdx.x * 2 + sub;
  const float d  = x[(size_t)b * F_ + f] - exu_b[f];
  const float em = emin[f];
  const bool is_zero = !(d > 0.f);
  const bool is_one  = (d > 0.f) && (d * em >= 1.f);
  float a[C_];
#pragma unroll
  for (int c = 0; c < C_; ++c) {
    const float zv = zlog[c * F_ + f];
    const float ov = olog[c * F_ + f];
    a[c] = is_zero ? zv : (is_one ? ov : 0.f);
  }
#pragma unroll
  for (int off = 32; off > 0; off >>= 1)
#pragma unroll
    for (int c = 0; c < C_; ++c) a[c] += __shfl_down(a[c], off);
  __shared__ float red[4][C_];
  __shared__ float lg[2][C_];
  const int wv_ = t >> 6, ln = t & 63;
  if (ln == 0)
#pragma unroll
    for (int c = 0; c < C_; ++c) red[wv_][c] = a[c];
  __syncthreads();
  if (t < 2 * C_) {
    const int rb = t / C_, c = t % C_;
    lg[rb][c] = red[rb * 2][c] + red[rb * 2 + 1][c]
              + logits_mid[(size_t)(blockIdx.x * 2 + rb) * C_ + c] + biasc[c];
  }
  __syncthreads();
  if (t < 2) {
    float mx = -3.0e38f;
#pragma unroll
    for (int c = 0; c < C_; ++c) mx = fmaxf(mx, lg[t][c]);
    float e[C_];
    float s = 0.f;
#pragma unroll
    for (int c = 0; c < C_; ++c) { e[c] = expf(lg[t][c] - mx); s += e[c]; }
    const float inv = 1.f / s;
#pragma unroll
    for (int c = 0; c < C_; ++c) out[(size_t)(blockIdx.x * 2 + t) * C_ + c] = e[c] * inv;
  }
}

extern "C" void kernel_launch(void* const* d_in, const int* in_sizes, int n_in,
                              void* d_out, int out_size, void* d_ws, size_t ws_size,
                              hipStream_t stream)
{
  const float* x     = (const float*)d_in[0];
  const float* exu_w = (const float*)d_in[1];
  const float* exu_b = (const float*)d_in[2];
  const float* W1    = (const float*)d_in[3];
  const float* b1    = (const float*)d_in[4];
  const float* W2    = (const float*)d_in[5];
  const float* b2    = (const float*)d_in[6];
  const float* b_out = (const float*)d_in[7];
  float* out = (float*)d_out;

  char* ws = (char*)d_ws;
  float* emin       = (float*)(ws + 0);                       //  512 B
  float* biasc      = (float*)(ws + 512);                     //   40 B
  int*   count      = (int*)  (ws + 1024);                    //  512 B
  int*   listb      = (int*)  (ws + 2048);                    //  1 MB
  float* sliceS     = (float*)(ws + 1050624);                 //  2 MB (128*8*512*4)
  float* sliceT     = (float*)(ws + 3147776);                 //  2 MB
  float* zlog       = (float*)(ws + 5244928);                 //  5 KB
  float* olog       = (float*)(ws + 5250048);                 //  5 KB
  float* logits_mid = (float*)(ws + 5255168);                 // 80 KB
  unsigned long long* skeys_g = (unsigned long long*)(ws + 5337088);  // 1 MB
  int*   rnk        = (int*)  (ws + 6385664);                 //  1 MB
  float* ddv        = (float*)(ws + 7434240);                 //  1 MB
  int*   bout       = (int*)  (ws + 8482816);                 //  1 MB -> ends ~9.5 MB
  float* h2pre      = (float*)(ws + 16777216);                // up to 512 MB worst case

  nam_sort<<<F_ + 1 + (B_ * C_ / 256), 256, 0, stream>>>(exu_w, b2, b_out, skeys_g,
                                                          emin, biasc, count, logits_mid);
  nam_classify<<<B_ / 2, 256, 0, stream>>>(x, exu_b, emin, count, listb);
  nam_stream2<<<F_ * NSL, 256, 0, stream>>>(x, exu_b, W1, skeys_g, listb, count,
                                             sliceS, sliceT, h2pre, rnk, ddv, bout);
  nam_finmid<<<F_, 256, 0, stream>>>(count, rnk, ddv, bout, h2pre, sliceS, sliceT,
                                      b1, W2, zlog, olog, logits_mid);
  nam_final<<<B_ / 2, 256, 0, stream>>>(x, exu_b, emin, zlog, olog, biasc, logits_mid, out);
}